// Round 8
// baseline (237.521 us; speedup 1.0000x reference)
//
#include <hip/hip_runtime.h>
#include <hip/hip_bf16.h>

#define N_NODES 50000
#define N_EDGES 1600000
#define NREL    16
#define DIM     64

#define BKT_SZ  16            // fused2 dst-tile
#define NTILE   3125          // 50000/16
#define NSEG_AL 50049         // max seg index 50047 (cb=390,tl=7) + 1

#define CB_SH   7             // coarse bucket = dst>>7 (128 dsts)
#define NCB     391           // ceil(50000/128)
#define P1_CHUNK 2048
#define P1_GRID  782          // ceil(1.6M/2048)

#define CB_ARENA 8704         // fixed per-cb arena: max run ~4400 + 128*31 pad
#define EMAX    (NCB * CB_ARENA)   // 3,403,264 slots
#define PREP_HBLK 3125        // 3.2M h elems / 1024 per block
#define SCAN_B  8             // buckets per bscan1 block

typedef __attribute__((ext_vector_type(8))) short short8;
typedef __attribute__((ext_vector_type(4))) float float4v;
typedef __attribute__((ext_vector_type(4))) unsigned short ushort4v;
typedef __attribute__((ext_vector_type(8))) unsigned short ushort8;

template<int IS_F32>
__device__ __forceinline__ float ldx(const void* p, size_t i) {
    if (IS_F32) {
        return ((const float*)p)[i];
    } else {
        unsigned short u = ((const unsigned short*)p)[i];
        return __uint_as_float(((unsigned)u) << 16);
    }
}

__device__ __forceinline__ float bfbits2f(unsigned short u) {
    return __uint_as_float(((unsigned)u) << 16);
}

__device__ __forceinline__ unsigned short f2bfbits(float v) {
    __hip_bfloat16 b = __float2bfloat16(v);
    unsigned short us; __builtin_memcpy(&us, &b, 2);
    return us;
}

// ---------------------------------------------------------------------------
// Dtype detector (proven): flag=1 if f32 dataset, 0 if bf16.
// ---------------------------------------------------------------------------
__global__ __launch_bounds__(1024) void k_detect(
    const float* __restrict__ norm_f, int* __restrict__ flag)
{
    __shared__ int sbad;
    if (threadIdx.x == 0) sbad = 0;
    __syncthreads();
    float v = norm_f[threadIdx.x];
    int bad = (v != v || fabsf(v) > 1e3f) ? 1 : 0;
    if (bad) atomicOr(&sbad, 1);
    __syncthreads();
    if (threadIdx.x == 0) *flag = sbad ? 0 : 1;
}

// ---------------------------------------------------------------------------
// BHIST+PREP merged (proven R7).
// ---------------------------------------------------------------------------
__global__ __launch_bounds__(256) void k_bhist_prep(
    const int* __restrict__ dst, int* __restrict__ H,
    const void* __restrict__ h_raw, const void* __restrict__ w_raw,
    unsigned short* __restrict__ hbf, unsigned short* __restrict__ Wswz,
    const int* __restrict__ flag)
{
    __shared__ int hist[NCB];
    const int blk = blockIdx.x;
    if (blk < P1_GRID) {
        for (int i = threadIdx.x; i < NCB; i += 256) hist[i] = 0;
        __syncthreads();
        const int e0 = blk * P1_CHUNK;
        for (int i = threadIdx.x; i < P1_CHUNK; i += 256) {
            int e = e0 + i;
            if (e < N_EDGES) atomicAdd(&hist[dst[e] >> CB_SH], 1);
        }
        __syncthreads();
        for (int b = threadIdx.x; b < NCB; b += 256)
            H[blk * NCB + b] = hist[b];
    } else {
        const int f = *flag;
        const int blk2 = blk - P1_GRID;
        if (blk2 < PREP_HBLK) {
            int i0 = blk2 * 1024 + threadIdx.x * 4;
            if (f) {
                float4 v = *(const float4*)((const float*)h_raw + i0);
                ushort4v o;
                o[0] = f2bfbits(v.x); o[1] = f2bfbits(v.y);
                o[2] = f2bfbits(v.z); o[3] = f2bfbits(v.w);
                *(ushort4v*)(hbf + i0) = o;
            } else {
                *(uint2*)(hbf + i0) = *(const uint2*)((const unsigned short*)h_raw + i0);
            }
        } else {
            int rel = blk2 - PREP_HBLK;
            for (int idx = threadIdx.x; idx < 4096; idx += 256) {
                int d = idx >> 6, o = idx & 63;
                float wv = f ? ((const float*)w_raw)[(size_t)((rel << 6) + d) * 64 + o]
                             : bfbits2f(((const unsigned short*)w_raw)[(size_t)((rel << 6) + d) * 64 + o]);
                int c = d >> 5, q = (d >> 3) & 3, j = d & 7;
                Wswz[(size_t)rel * 5120 + ((c << 6) + o) * 40 + q * 8 + j] = f2bfbits(wv);
            }
        }
    }
}

// ---------------------------------------------------------------------------
// BSCAN1 v2: 8 buckets per block (H read 8-wide: ~8x less effective line
// traffic) + transposed OTT output so k_p1's read is one coalesced row.
// ---------------------------------------------------------------------------
__global__ __launch_bounds__(256) void k_bscan1(
    const int* __restrict__ H, int* __restrict__ OTT, int* __restrict__ tot)
{
    __shared__ int col[SCAN_B][P1_GRID];   // 25 KB
    const int b0 = blockIdx.x * SCAN_B;
    const int nb = min(SCAN_B, NCB - b0);
    for (int i = threadIdx.x; i < P1_GRID; i += 256) {
        const int* hp = H + (size_t)i * NCB + b0;
#pragma unroll
        for (int j = 0; j < SCAN_B; ++j)
            if (j < nb) col[j][i] = hp[j];
    }
    __syncthreads();
    const int wave = threadIdx.x >> 6, lane = threadIdx.x & 63;
    for (int j = wave; j < nb; j += 4) {
        int carry = 0;
        for (int chunk = 0; chunk < (P1_GRID + 63) / 64; ++chunk) {
            int i = chunk * 64 + lane;
            int c = (i < P1_GRID) ? col[j][i] : 0;
            int incl = c;
#pragma unroll
            for (int off = 1; off < 64; off <<= 1) {
                int t = __shfl_up(incl, off, 64);
                if (lane >= off) incl += t;
            }
            if (i < P1_GRID) col[j][i] = carry + incl - c;
            carry += __shfl(incl, 63, 64);
        }
        if (lane == 0) tot[b0 + j] = carry;
    }
    __syncthreads();
    for (int i = threadIdx.x; i < P1_GRID; i += 256) {
        int* op = OTT + (size_t)i * NCB + b0;
#pragma unroll
        for (int j = 0; j < SCAN_B; ++j)
            if (j < nb) op[j] = col[j][i];
    }
}

__global__ __launch_bounds__(64) void k_bscan2(
    const int* __restrict__ tot, int* __restrict__ base)
{
    const int lane = threadIdx.x;
    int carry = 0;
    for (int chunk = 0; chunk < (NCB + 63) / 64; ++chunk) {
        int i = chunk * 64 + lane;
        int c = (i < NCB) ? tot[i] : 0;
        int incl = c;
#pragma unroll
        for (int off = 1; off < 64; off <<= 1) {
            int t = __shfl_up(incl, off, 64);
            if (lane >= off) incl += t;
        }
        if (i < NCB) base[i] = carry + incl - c;
        carry += __shfl(incl, 63, 64);
    }
    if (lane == 0) base[NCB] = carry;   // == N_EDGES
}

// ---------------------------------------------------------------------------
// P1 (proven): multisplit into coarse bucket runs; OTT read now coalesced.
// rec: [6:0]=dst&127, [23:8]=src, [27:24]=rel, [47:32]=norm bf16.
// ---------------------------------------------------------------------------
template<int IS_F32>
__device__ __forceinline__ void p1_body(
    const int* __restrict__ src, const int* __restrict__ dst,
    const int* __restrict__ rel, const void* __restrict__ norm_raw,
    const int* __restrict__ base, const int* __restrict__ OTT,
    unsigned long long* __restrict__ R, int* curs)
{
    const int blk = blockIdx.x;
    for (int b = threadIdx.x; b < NCB; b += 256)
        curs[b] = base[b] + OTT[(size_t)blk * NCB + b];
    __syncthreads();
    const int e0 = blk * P1_CHUNK;
    for (int i = threadIdx.x; i < P1_CHUNK; i += 256) {
        int e = e0 + i;
        if (e >= N_EDGES) continue;
        int d = dst[e];
        int pos = atomicAdd(&curs[d >> CB_SH], 1);
        unsigned short nb = f2bfbits(ldx<IS_F32>(norm_raw, e));
        unsigned long long rec =
              (unsigned long long)(d & 127)
            | ((unsigned long long)(unsigned)src[e] << 8)
            | ((unsigned long long)(unsigned)rel[e] << 24)
            | ((unsigned long long)nb << 32);
        R[pos] = rec;
    }
}

__global__ __launch_bounds__(256) void k_p1(
    const int* __restrict__ src, const int* __restrict__ dst,
    const int* __restrict__ rel, const void* __restrict__ norm_raw,
    const int* __restrict__ base, const int* __restrict__ OTT,
    unsigned long long* __restrict__ R, const int* __restrict__ flag)
{
    __shared__ int curs[NCB];
    if (*flag) p1_body<1>(src, dst, rel, norm_raw, base, OTT, R, curs);
    else       p1_body<0>(src, dst, rel, norm_raw, base, OTT, R, curs);
}

// ---------------------------------------------------------------------------
// FINE (proven R7): merged hist+place into fixed per-cb arena.
// ---------------------------------------------------------------------------
__global__ __launch_bounds__(256) void k_fine(
    const int* __restrict__ base,
    const unsigned long long* __restrict__ R,
    unsigned* __restrict__ packed2, unsigned short* __restrict__ normS,
    int* __restrict__ segBase, int* __restrict__ segCnt)
{
    __shared__ int cnt[128], sbl[128], curs[128];
    const int tid = threadIdx.x, cb = blockIdx.x;
    if (tid < 128) { cnt[tid] = 0; curs[tid] = 0; }
    __syncthreads();
    const int c0 = base[cb], c1 = base[cb + 1];

    for (int i = c0 + tid; i < c1; i += 256) {
        unsigned long long rec = R[i];
        int bin = (int)((rec >> 24) & 15) * 8 + (int)((rec >> 4) & 7);
        atomicAdd(&cnt[bin], 1);
    }
    __syncthreads();

    if (tid == 0) {
        int g = cb * CB_ARENA;
        for (int j = 0; j < 128; ++j) {
            sbl[j] = g;
            g += (cnt[j] + 31) & ~31;
        }
    }
    __syncthreads();

    if (tid < 128) {
        int seg = ((cb * 8 + (tid & 7)) << 4) + (tid >> 3);   // tile*16 + rel
        segBase[seg] = sbl[tid];
        segCnt[seg]  = cnt[tid];
    }

    for (int i = c0 + tid; i < c1; i += 256) {
        unsigned long long rec = R[i];
        int bin = (int)((rec >> 24) & 15) * 8 + (int)((rec >> 4) & 7);
        int pos = sbl[bin] + atomicAdd(&curs[bin], 1);
        packed2[pos] = (unsigned)rec & 0x00FFFF0Fu;   // (dst&15) | (src<<8)
        normS[pos]   = (unsigned short)(rec >> 32);
    }
    __syncthreads();

    for (int p = tid; p < 128 * 32; p += 256) {
        int bin = p >> 5, j = p & 31;
        int c = cnt[bin], pe = (c + 31) & ~31;
        if (j < pe - c) {
            int pos = sbl[bin] + c + j;
            packed2[pos] = 0;
            normS[pos]   = 0;
        }
    }
}

// ---------------------------------------------------------------------------
// K_FUSED2 v4: 2 waves/tile (proven R7) + depth-1 software pipeline over the
// flattened (rel, chunk) stream: next chunk's pa/pb/norm loads issue before
// current chunk's gathers/MFMAs and before segment tails, hiding L2 latency.
// ---------------------------------------------------------------------------
#define MFMA_BF16 __builtin_amdgcn_mfma_f32_16x16x32_bf16

__global__ __launch_bounds__(256) void k_fused2(
    const unsigned* __restrict__ packed2,
    const unsigned short* __restrict__ normS,
    const unsigned short* __restrict__ hbf,
    const unsigned short* __restrict__ Wswz,
    const int* __restrict__ segBase,
    const int* __restrict__ segCnt,
    void* __restrict__ out, const int* __restrict__ flag)
{
    __shared__ __align__(16) unsigned short sbuf[4][16 * 72];
    __shared__ float pbuf[2][64][17];
    const int tid  = threadIdx.x;
    const int lane = tid & 63, wave = tid >> 6;
    const int n15  = lane & 15, quad = lane >> 4;
    const int tin  = wave >> 1;          // tile within block
    const int half = wave & 1;           // rel half
    const int tile = blockIdx.x * 2 + tin;
    const bool valid = (tile < NTILE);

    float4v ac0 = {0.f,0.f,0.f,0.f}, ac1 = {0.f,0.f,0.f,0.f};
    float4v ac2 = {0.f,0.f,0.f,0.f}, ac3 = {0.f,0.f,0.f,0.f};
    unsigned short* sb_ = &sbuf[wave][0];

    if (valid) {
        const int r0 = half * 8;
        const int sidx = tile * 16;
        int r = r0 - 1, c = 0, nch = 0, sgb = 0;

        // Advance to next chunk of the flattened (rel, chunk) stream.
        auto advance = [&]() -> bool {
            if (++c < nch) return true;
            for (++r; r < r0 + 8; ++r) {
                int sc = segCnt[sidx + r];
                if (sc > 0) {
                    nch = (sc + 31) >> 5;
                    c = 0;
                    sgb = segBase[sidx + r];
                    return true;
                }
            }
            return false;
        };

        bool have = advance();
        uint4 pa = {0,0,0,0}, pb = {0,0,0,0};
        ushort8 nmv = {0,0,0,0,0,0,0,0};
        if (have) {
            const int e0 = sgb + (c << 5) + (quad << 3);
            pa  = *(const uint4*)(packed2 + e0);
            pb  = *(const uint4*)(packed2 + e0 + 4);
            nmv = *(const ushort8*)(normS + e0);
        }

        float4v s0 = {0.f,0.f,0.f,0.f}, s1 = {0.f,0.f,0.f,0.f};
        float4v s2 = {0.f,0.f,0.f,0.f}, s3 = {0.f,0.f,0.f,0.f};

        while (have) {
            const int rcur = r;
            const bool nhave = advance();
            uint4 pa2 = {0,0,0,0}, pb2 = {0,0,0,0};
            ushort8 nm2 = {0,0,0,0,0,0,0,0};
            if (nhave) {
                const int e1 = sgb + (c << 5) + (quad << 3);
                pa2 = *(const uint4*)(packed2 + e1);
                pb2 = *(const uint4*)(packed2 + e1 + 4);
                nm2 = *(const ushort8*)(normS + e1);
            }

            // ---- current chunk compute (pa/pb/nmv already in flight) ----
            const unsigned short* h0 = hbf + (size_t)(pa.x >> 8) * 64 + n15;
            const unsigned short* h1 = hbf + (size_t)(pa.y >> 8) * 64 + n15;
            const unsigned short* h2 = hbf + (size_t)(pa.z >> 8) * 64 + n15;
            const unsigned short* h3 = hbf + (size_t)(pa.w >> 8) * 64 + n15;
            const unsigned short* h4 = hbf + (size_t)(pb.x >> 8) * 64 + n15;
            const unsigned short* h5 = hbf + (size_t)(pb.y >> 8) * 64 + n15;
            const unsigned short* h6 = hbf + (size_t)(pb.z >> 8) * 64 + n15;
            const unsigned short* h7 = hbf + (size_t)(pb.w >> 8) * 64 + n15;

            short8 av;
            av[0] = ((int)(pa.x & 15u) == n15) ? (short)nmv[0] : (short)0;
            av[1] = ((int)(pa.y & 15u) == n15) ? (short)nmv[1] : (short)0;
            av[2] = ((int)(pa.z & 15u) == n15) ? (short)nmv[2] : (short)0;
            av[3] = ((int)(pa.w & 15u) == n15) ? (short)nmv[3] : (short)0;
            av[4] = ((int)(pb.x & 15u) == n15) ? (short)nmv[4] : (short)0;
            av[5] = ((int)(pb.y & 15u) == n15) ? (short)nmv[5] : (short)0;
            av[6] = ((int)(pb.z & 15u) == n15) ? (short)nmv[6] : (short)0;
            av[7] = ((int)(pb.w & 15u) == n15) ? (short)nmv[7] : (short)0;

#define GATHER_MFMA(S, OFF) \
            { short8 bv; \
              bv[0] = (short)h0[OFF]; bv[1] = (short)h1[OFF]; \
              bv[2] = (short)h2[OFF]; bv[3] = (short)h3[OFF]; \
              bv[4] = (short)h4[OFF]; bv[5] = (short)h5[OFF]; \
              bv[6] = (short)h6[OFF]; bv[7] = (short)h7[OFF]; \
              S = MFMA_BF16(av, bv, S, 0, 0, 0); }

            GATHER_MFMA(s0, 0)
            GATHER_MFMA(s1, 16)
            GATHER_MFMA(s2, 32)
            GATHER_MFMA(s3, 48)
#undef GATHER_MFMA

            // ---- segment tail (next chunk's loads already in flight) ----
            if (!nhave || r != rcur) {
#pragma unroll
                for (int i = 0; i < 4; ++i) {
                    sb_[(quad * 4 + i) * 72 +  0 + n15] = f2bfbits(s0[i]);
                    sb_[(quad * 4 + i) * 72 + 16 + n15] = f2bfbits(s1[i]);
                    sb_[(quad * 4 + i) * 72 + 32 + n15] = f2bfbits(s2[i]);
                    sb_[(quad * 4 + i) * 72 + 48 + n15] = f2bfbits(s3[i]);
                }
                const short8 a0 = *(const short8*)(sb_ + n15 * 72 + quad * 8);
                const short8 a1 = *(const short8*)(sb_ + n15 * 72 + 32 + quad * 8);

                const unsigned short* wp = Wswz + (size_t)rcur * 5120;
                const short8 w00 = *(const short8*)(wp + ( 0 + n15) * 40 + quad * 8);
                const short8 w01 = *(const short8*)(wp + (16 + n15) * 40 + quad * 8);
                const short8 w02 = *(const short8*)(wp + (32 + n15) * 40 + quad * 8);
                const short8 w03 = *(const short8*)(wp + (48 + n15) * 40 + quad * 8);
                const short8 w10 = *(const short8*)(wp + (64 + n15) * 40 + quad * 8);
                const short8 w11 = *(const short8*)(wp + (80 + n15) * 40 + quad * 8);
                const short8 w12 = *(const short8*)(wp + (96 + n15) * 40 + quad * 8);
                const short8 w13 = *(const short8*)(wp + (112 + n15) * 40 + quad * 8);

                ac0 = MFMA_BF16(a0, w00, ac0, 0, 0, 0);
                ac1 = MFMA_BF16(a0, w01, ac1, 0, 0, 0);
                ac2 = MFMA_BF16(a0, w02, ac2, 0, 0, 0);
                ac3 = MFMA_BF16(a0, w03, ac3, 0, 0, 0);
                ac0 = MFMA_BF16(a1, w10, ac0, 0, 0, 0);
                ac1 = MFMA_BF16(a1, w11, ac1, 0, 0, 0);
                ac2 = MFMA_BF16(a1, w12, ac2, 0, 0, 0);
                ac3 = MFMA_BF16(a1, w13, ac3, 0, 0, 0);

                s0 = (float4v){0.f,0.f,0.f,0.f};
                s1 = (float4v){0.f,0.f,0.f,0.f};
                s2 = (float4v){0.f,0.f,0.f,0.f};
                s3 = (float4v){0.f,0.f,0.f,0.f};
            }

            pa = pa2; pb = pb2; nmv = nm2;
            have = nhave;
        }
    }

    // merge rel halves: odd wave publishes, even wave reduces + stores.
    if (half) {
#pragma unroll
        for (int i = 0; i < 4; ++i) {
            pbuf[tin][lane][i]      = ac0[i];
            pbuf[tin][lane][4 + i]  = ac1[i];
            pbuf[tin][lane][8 + i]  = ac2[i];
            pbuf[tin][lane][12 + i] = ac3[i];
        }
    }
    __syncthreads();
    if (!half && valid) {
#pragma unroll
        for (int i = 0; i < 4; ++i) {
            ac0[i] += pbuf[tin][lane][i];
            ac1[i] += pbuf[tin][lane][4 + i];
            ac2[i] += pbuf[tin][lane][8 + i];
            ac3[i] += pbuf[tin][lane][12 + i];
        }
        const int node0 = tile << 4;
        const int f = *flag;
#define STORE_T(AC, T) \
        { \
            _Pragma("unroll") \
            for (int i = 0; i < 4; ++i) { \
                float rv = fmaxf(AC[i], 0.f); \
                size_t ob = (size_t)(node0 + quad * 4 + i) * 64 + (T) * 16 + n15; \
                if (f) ((float*)out)[ob] = rv; \
                else   ((unsigned short*)out)[ob] = f2bfbits(rv); \
            } \
        }
        STORE_T(ac0, 0)
        STORE_T(ac1, 1)
        STORE_T(ac2, 2)
        STORE_T(ac3, 3)
#undef STORE_T
    }
}

// ---------------------------------------------------------------------------
extern "C" void kernel_launch(void* const* d_in, const int* in_sizes, int n_in,
                              void* d_out, int out_size, void* d_ws, size_t ws_size,
                              hipStream_t stream)
{
    const void* h      = d_in[0];
    const void* weight = d_in[1];
    const void* norm   = d_in[2];
    const int* src = (const int*)d_in[3];
    const int* dst = (const int*)d_in[4];
    const int* rel = (const int*)d_in[5];

    char* w = (char*)d_ws;
    int* flag = (int*)w;                        w += 256;
    int* base = (int*)w;                        w += ((NCB + 1) * 4 + 255) / 256 * 256;
    int* tot  = (int*)w;                        w += (NCB * 4 + 255) / 256 * 256;
    int* H    = (int*)w;                        w += ((size_t)P1_GRID * NCB * 4 + 255) / 256 * 256;
    int* OTT  = (int*)w;                        w += ((size_t)P1_GRID * NCB * 4 + 255) / 256 * 256;
    int* segBase = (int*)w;                     w += ((size_t)NSEG_AL * 4 + 255) / 256 * 256;
    int* segCnt  = (int*)w;                     w += ((size_t)NSEG_AL * 4 + 255) / 256 * 256;
    unsigned long long* R = (unsigned long long*)w;  w += (size_t)N_EDGES * 8;
    unsigned* packed2 = (unsigned*)w;           w += ((size_t)EMAX * 4 + 255) / 256 * 256;
    unsigned short* normS = (unsigned short*)w; w += ((size_t)EMAX * 2 + 255) / 256 * 256;
    unsigned short* hbf = (unsigned short*)w;   w += (size_t)N_NODES * DIM * 2;
    unsigned short* Wswz = (unsigned short*)w;  w += (size_t)NREL * 5120 * 2;

    k_detect<<<1, 1024, 0, stream>>>((const float*)norm, flag);

    k_bhist_prep<<<P1_GRID + PREP_HBLK + NREL, 256, 0, stream>>>(
        dst, H, h, weight, hbf, Wswz, flag);

    k_bscan1<<<(NCB + SCAN_B - 1) / SCAN_B, 256, 0, stream>>>(H, OTT, tot);
    k_bscan2<<<1, 64, 0, stream>>>(tot, base);

    k_p1<<<P1_GRID, 256, 0, stream>>>(src, dst, rel, norm, base, OTT, R, flag);

    k_fine<<<NCB, 256, 0, stream>>>(base, R, packed2, normS, segBase, segCnt);

    k_fused2<<<(NTILE + 1) / 2, 256, 0, stream>>>(packed2, normS, hbf, Wswz,
                                                  segBase, segCnt, d_out, flag);
}

// Round 9
// 213.142 us; speedup vs baseline: 1.1144x; 1.1144x over previous
//
#include <hip/hip_runtime.h>
#include <hip/hip_bf16.h>

#define N_NODES 50000
#define N_EDGES 1600000
#define NREL    16
#define DIM     64

#define BKT_SZ  16            // fused2 dst-tile
#define NTILE   3125          // 50000/16
#define NSEG_AL 50049         // max seg index 50047 (cb=390,tl=7) + 1

#define CB_SH   7             // coarse bucket = dst>>7 (128 dsts)
#define NCB     391           // ceil(50000/128)
#define P1_CHUNK 2048
#define P1_GRID  782          // ceil(1.6M/2048)

#define CB_R_ARENA 5120       // R slots per coarse bucket (mean 4096 + 16s)
#define CB_ARENA 8704         // packed2 arena per cb: max run + 128*31 pad
#define EMAX    (NCB * CB_ARENA)   // 3,403,264 slots
#define PREP_HBLK 3125        // 3.2M h elems / 1024 per block

typedef __attribute__((ext_vector_type(8))) short short8;
typedef __attribute__((ext_vector_type(4))) float float4v;
typedef __attribute__((ext_vector_type(4))) unsigned short ushort4v;

template<int IS_F32>
__device__ __forceinline__ float ldx(const void* p, size_t i) {
    if (IS_F32) {
        return ((const float*)p)[i];
    } else {
        unsigned short u = ((const unsigned short*)p)[i];
        return __uint_as_float(((unsigned)u) << 16);
    }
}

__device__ __forceinline__ float bfbits2f(unsigned short u) {
    return __uint_as_float(((unsigned)u) << 16);
}

__device__ __forceinline__ unsigned short f2bfbits(float v) {
    __hip_bfloat16 b = __float2bfloat16(v);
    unsigned short us; __builtin_memcpy(&us, &b, 2);
    return us;
}

// ---------------------------------------------------------------------------
// Dtype detector (proven) + gcur zeroing (391 ints, free here).
// ---------------------------------------------------------------------------
__global__ __launch_bounds__(1024) void k_detect(
    const float* __restrict__ norm_f, int* __restrict__ flag,
    int* __restrict__ gcur)
{
    __shared__ int sbad;
    if (threadIdx.x == 0) sbad = 0;
    if (threadIdx.x < NCB) gcur[threadIdx.x] = 0;
    __syncthreads();
    float v = norm_f[threadIdx.x];
    int bad = (v != v || fabsf(v) > 1e3f) ? 1 : 0;
    if (bad) atomicOr(&sbad, 1);
    __syncthreads();
    if (threadIdx.x == 0) *flag = sbad ? 0 : 1;
}

// ---------------------------------------------------------------------------
// SPLIT+PREP: one launch replaces bhist/bscan1/bscan2/p1/prep.
// Blocks [0,P1_GRID): chunk LDS-hist -> one atomic reservation per
// (block,bucket) into fixed per-cb R arenas -> LDS-cursor placement.
// Order within a bucket is nondeterministic; downstream only needs
// bucket membership (fine re-bins, fused2 sums order-independently).
// Blocks beyond: h->bf16 copy and W->pre-swizzled fragments (proven).
// ---------------------------------------------------------------------------
template<int IS_F32>
__device__ __forceinline__ void split_body(
    const int* __restrict__ src, const int* __restrict__ dst,
    const int* __restrict__ rel, const void* __restrict__ norm_raw,
    int* __restrict__ gcur, unsigned long long* __restrict__ R,
    int* hist, int* curs)
{
    const int blk = blockIdx.x;
    for (int i = threadIdx.x; i < NCB; i += 256) hist[i] = 0;
    __syncthreads();
    const int e0 = blk * P1_CHUNK;
    for (int i = threadIdx.x; i < P1_CHUNK; i += 256) {
        int e = e0 + i;
        if (e < N_EDGES) atomicAdd(&hist[dst[e] >> CB_SH], 1);
    }
    __syncthreads();
    for (int b = threadIdx.x; b < NCB; b += 256) {
        int c = hist[b];
        if (c > 0) {
            int s = atomicAdd(&gcur[b], c);
            if (s + c > CB_R_ARENA) s = CB_R_ARENA - c;   // OOB guard
            curs[b] = b * CB_R_ARENA + s;
        }
    }
    __syncthreads();
    for (int i = threadIdx.x; i < P1_CHUNK; i += 256) {
        int e = e0 + i;
        if (e >= N_EDGES) continue;
        int d = dst[e];
        int pos = atomicAdd(&curs[d >> CB_SH], 1);
        unsigned short nb = f2bfbits(ldx<IS_F32>(norm_raw, e));
        unsigned long long rec =
              (unsigned long long)(d & 127)
            | ((unsigned long long)(unsigned)src[e] << 8)
            | ((unsigned long long)(unsigned)rel[e] << 24)
            | ((unsigned long long)nb << 32);
        R[pos] = rec;
    }
}

__global__ __launch_bounds__(256) void k_split_prep(
    const int* __restrict__ src, const int* __restrict__ dst,
    const int* __restrict__ rel, const void* __restrict__ norm_raw,
    int* __restrict__ gcur, unsigned long long* __restrict__ R,
    const void* __restrict__ h_raw, const void* __restrict__ w_raw,
    unsigned short* __restrict__ hbf, unsigned short* __restrict__ Wswz,
    const int* __restrict__ flag)
{
    __shared__ int hist[NCB];
    __shared__ int curs[NCB];
    const int blk = blockIdx.x;
    if (blk < P1_GRID) {
        if (*flag) split_body<1>(src, dst, rel, norm_raw, gcur, R, hist, curs);
        else       split_body<0>(src, dst, rel, norm_raw, gcur, R, hist, curs);
    } else {
        const int f = *flag;
        const int blk2 = blk - P1_GRID;
        if (blk2 < PREP_HBLK) {
            int i0 = blk2 * 1024 + threadIdx.x * 4;
            if (f) {
                float4 v = *(const float4*)((const float*)h_raw + i0);
                ushort4v o;
                o[0] = f2bfbits(v.x); o[1] = f2bfbits(v.y);
                o[2] = f2bfbits(v.z); o[3] = f2bfbits(v.w);
                *(ushort4v*)(hbf + i0) = o;
            } else {
                *(uint2*)(hbf + i0) = *(const uint2*)((const unsigned short*)h_raw + i0);
            }
        } else {
            int rel2 = blk2 - PREP_HBLK;
            for (int idx = threadIdx.x; idx < 4096; idx += 256) {
                int d = idx >> 6, o = idx & 63;
                float wv = f ? ((const float*)w_raw)[(size_t)((rel2 << 6) + d) * 64 + o]
                             : bfbits2f(((const unsigned short*)w_raw)[(size_t)((rel2 << 6) + d) * 64 + o]);
                int c = d >> 5, q = (d >> 3) & 3, j = d & 7;
                Wswz[(size_t)rel2 * 5120 + ((c << 6) + o) * 40 + q * 8 + j] = f2bfbits(wv);
            }
        }
    }
}

// ---------------------------------------------------------------------------
// FINE (proven R7 structure): per-cb R run -> 128 (rel,tile) bins in the
// packed arena. Bucket extent now comes from gcur (fixed arena base).
// ---------------------------------------------------------------------------
__global__ __launch_bounds__(256) void k_fine(
    const int* __restrict__ gcur,
    const unsigned long long* __restrict__ R,
    unsigned* __restrict__ packed2, unsigned short* __restrict__ normS,
    int* __restrict__ segBase, int* __restrict__ segCnt)
{
    __shared__ int cnt[128], sbl[128], curs[128];
    const int tid = threadIdx.x, cb = blockIdx.x;
    if (tid < 128) { cnt[tid] = 0; curs[tid] = 0; }
    __syncthreads();
    const int c0 = cb * CB_R_ARENA;
    const int c1 = c0 + min(gcur[cb], CB_R_ARENA);

    for (int i = c0 + tid; i < c1; i += 256) {
        unsigned long long rec = R[i];
        int bin = (int)((rec >> 24) & 15) * 8 + (int)((rec >> 4) & 7);
        atomicAdd(&cnt[bin], 1);
    }
    __syncthreads();

    if (tid == 0) {
        int g = cb * CB_ARENA;
        for (int j = 0; j < 128; ++j) {
            sbl[j] = g;
            g += (cnt[j] + 31) & ~31;
        }
    }
    __syncthreads();

    if (tid < 128) {
        int seg = ((cb * 8 + (tid & 7)) << 4) + (tid >> 3);   // tile*16 + rel
        segBase[seg] = sbl[tid];
        segCnt[seg]  = cnt[tid];
    }

    for (int i = c0 + tid; i < c1; i += 256) {
        unsigned long long rec = R[i];
        int bin = (int)((rec >> 24) & 15) * 8 + (int)((rec >> 4) & 7);
        int pos = sbl[bin] + atomicAdd(&curs[bin], 1);
        packed2[pos] = (unsigned)rec & 0x00FFFF0Fu;   // (dst&15) | (src<<8)
        normS[pos]   = (unsigned short)(rec >> 32);
    }
    __syncthreads();

    for (int p = tid; p < 128 * 32; p += 256) {
        int bin = p >> 5, j = p & 31;
        int c = cnt[bin], pe = (c + 31) & ~31;
        if (j < pe - c) {
            int pos = sbl[bin] + c + j;
            packed2[pos] = 0;
            normS[pos]   = 0;
        }
    }
}

// ---------------------------------------------------------------------------
// K_FUSED2 (exact R7-proven body, 59us/VGPR56): 2 waves per 16-dst tile
// (rel halves 0-7 / 8-15), partials merged via LDS. R8's pipeline variant
// regressed (VGPR 80, occupancy -22%) and is reverted.
// ---------------------------------------------------------------------------
#define MFMA_BF16 __builtin_amdgcn_mfma_f32_16x16x32_bf16

__global__ __launch_bounds__(256) void k_fused2(
    const unsigned* __restrict__ packed2,
    const unsigned short* __restrict__ normS,
    const unsigned short* __restrict__ hbf,
    const unsigned short* __restrict__ Wswz,
    const int* __restrict__ segBase,
    const int* __restrict__ segCnt,
    void* __restrict__ out, const int* __restrict__ flag)
{
    __shared__ __align__(16) unsigned short sbuf[4][16 * 72];
    __shared__ float pbuf[2][64][17];
    const int tid  = threadIdx.x;
    const int lane = tid & 63, wave = tid >> 6;
    const int n15  = lane & 15, quad = lane >> 4;
    const int tin  = wave >> 1;          // tile within block
    const int half = wave & 1;           // rel half
    const int tile = blockIdx.x * 2 + tin;
    const bool valid = (tile < NTILE);

    float4v ac0 = {0.f,0.f,0.f,0.f}, ac1 = {0.f,0.f,0.f,0.f};
    float4v ac2 = {0.f,0.f,0.f,0.f}, ac3 = {0.f,0.f,0.f,0.f};
    unsigned short* sb_ = &sbuf[wave][0];

    if (valid) {
        const int r0 = half * 8;
        for (int r = r0; r < r0 + 8; ++r) {
            const int sgb  = segBase[tile * 16 + r];
            const int scnt = segCnt[tile * 16 + r];
            if (scnt == 0) continue;
            const int nch = (scnt + 31) >> 5;

            float4v s0 = {0.f,0.f,0.f,0.f}, s1 = {0.f,0.f,0.f,0.f};
            float4v s2 = {0.f,0.f,0.f,0.f}, s3 = {0.f,0.f,0.f,0.f};

            for (int c = 0; c < nch; ++c) {
                const int e0 = sgb + (c << 5) + (quad << 3);
                const uint4 pa = *(const uint4*)(packed2 + e0);
                const uint4 pb = *(const uint4*)(packed2 + e0 + 4);
                const ushort4v na = *(const ushort4v*)(normS + e0);
                const ushort4v nb = *(const ushort4v*)(normS + e0 + 4);

                const unsigned short* h0 = hbf + (size_t)(pa.x >> 8) * 64 + n15;
                const unsigned short* h1 = hbf + (size_t)(pa.y >> 8) * 64 + n15;
                const unsigned short* h2 = hbf + (size_t)(pa.z >> 8) * 64 + n15;
                const unsigned short* h3 = hbf + (size_t)(pa.w >> 8) * 64 + n15;
                const unsigned short* h4 = hbf + (size_t)(pb.x >> 8) * 64 + n15;
                const unsigned short* h5 = hbf + (size_t)(pb.y >> 8) * 64 + n15;
                const unsigned short* h6 = hbf + (size_t)(pb.z >> 8) * 64 + n15;
                const unsigned short* h7 = hbf + (size_t)(pb.w >> 8) * 64 + n15;

                short8 av;
                av[0] = ((int)(pa.x & 15u) == n15) ? (short)na[0] : (short)0;
                av[1] = ((int)(pa.y & 15u) == n15) ? (short)na[1] : (short)0;
                av[2] = ((int)(pa.z & 15u) == n15) ? (short)na[2] : (short)0;
                av[3] = ((int)(pa.w & 15u) == n15) ? (short)na[3] : (short)0;
                av[4] = ((int)(pb.x & 15u) == n15) ? (short)nb[0] : (short)0;
                av[5] = ((int)(pb.y & 15u) == n15) ? (short)nb[1] : (short)0;
                av[6] = ((int)(pb.z & 15u) == n15) ? (short)nb[2] : (short)0;
                av[7] = ((int)(pb.w & 15u) == n15) ? (short)nb[3] : (short)0;

#define GATHER_MFMA(S, OFF) \
                { short8 bv; \
                  bv[0] = (short)h0[OFF]; bv[1] = (short)h1[OFF]; \
                  bv[2] = (short)h2[OFF]; bv[3] = (short)h3[OFF]; \
                  bv[4] = (short)h4[OFF]; bv[5] = (short)h5[OFF]; \
                  bv[6] = (short)h6[OFF]; bv[7] = (short)h7[OFF]; \
                  S = MFMA_BF16(av, bv, S, 0, 0, 0); }

                GATHER_MFMA(s0, 0)
                GATHER_MFMA(s1, 16)
                GATHER_MFMA(s2, 32)
                GATHER_MFMA(s3, 48)
#undef GATHER_MFMA
            }

            // repack s (C layout: row=quad*4+i, col=t*16+n15) -> LDS row-major
#pragma unroll
            for (int i = 0; i < 4; ++i) {
                sb_[(quad * 4 + i) * 72 +  0 + n15] = f2bfbits(s0[i]);
                sb_[(quad * 4 + i) * 72 + 16 + n15] = f2bfbits(s1[i]);
                sb_[(quad * 4 + i) * 72 + 32 + n15] = f2bfbits(s2[i]);
                sb_[(quad * 4 + i) * 72 + 48 + n15] = f2bfbits(s3[i]);
            }

            // A-frags: row=n15, k-chunk=quad (k1-proven layout)
            const short8 a0 = *(const short8*)(sb_ + n15 * 72 + quad * 8);
            const short8 a1 = *(const short8*)(sb_ + n15 * 72 + 32 + quad * 8);

            const unsigned short* wp = Wswz + (size_t)r * 5120;
            const short8 w00 = *(const short8*)(wp + ( 0 + n15) * 40 + quad * 8);
            const short8 w01 = *(const short8*)(wp + (16 + n15) * 40 + quad * 8);
            const short8 w02 = *(const short8*)(wp + (32 + n15) * 40 + quad * 8);
            const short8 w03 = *(const short8*)(wp + (48 + n15) * 40 + quad * 8);
            const short8 w10 = *(const short8*)(wp + (64 + n15) * 40 + quad * 8);
            const short8 w11 = *(const short8*)(wp + (80 + n15) * 40 + quad * 8);
            const short8 w12 = *(const short8*)(wp + (96 + n15) * 40 + quad * 8);
            const short8 w13 = *(const short8*)(wp + (112 + n15) * 40 + quad * 8);

            ac0 = MFMA_BF16(a0, w00, ac0, 0, 0, 0);
            ac1 = MFMA_BF16(a0, w01, ac1, 0, 0, 0);
            ac2 = MFMA_BF16(a0, w02, ac2, 0, 0, 0);
            ac3 = MFMA_BF16(a0, w03, ac3, 0, 0, 0);
            ac0 = MFMA_BF16(a1, w10, ac0, 0, 0, 0);
            ac1 = MFMA_BF16(a1, w11, ac1, 0, 0, 0);
            ac2 = MFMA_BF16(a1, w12, ac2, 0, 0, 0);
            ac3 = MFMA_BF16(a1, w13, ac3, 0, 0, 0);
        }
    }

    // merge rel halves: odd wave publishes, even wave reduces + stores.
    if (half) {
#pragma unroll
        for (int i = 0; i < 4; ++i) {
            pbuf[tin][lane][i]      = ac0[i];
            pbuf[tin][lane][4 + i]  = ac1[i];
            pbuf[tin][lane][8 + i]  = ac2[i];
            pbuf[tin][lane][12 + i] = ac3[i];
        }
    }
    __syncthreads();
    if (!half && valid) {
#pragma unroll
        for (int i = 0; i < 4; ++i) {
            ac0[i] += pbuf[tin][lane][i];
            ac1[i] += pbuf[tin][lane][4 + i];
            ac2[i] += pbuf[tin][lane][8 + i];
            ac3[i] += pbuf[tin][lane][12 + i];
        }
        const int node0 = tile << 4;
        const int f = *flag;
#define STORE_T(AC, T) \
        { \
            _Pragma("unroll") \
            for (int i = 0; i < 4; ++i) { \
                float rv = fmaxf(AC[i], 0.f); \
                size_t ob = (size_t)(node0 + quad * 4 + i) * 64 + (T) * 16 + n15; \
                if (f) ((float*)out)[ob] = rv; \
                else   ((unsigned short*)out)[ob] = f2bfbits(rv); \
            } \
        }
        STORE_T(ac0, 0)
        STORE_T(ac1, 1)
        STORE_T(ac2, 2)
        STORE_T(ac3, 3)
#undef STORE_T
    }
}

// ---------------------------------------------------------------------------
extern "C" void kernel_launch(void* const* d_in, const int* in_sizes, int n_in,
                              void* d_out, int out_size, void* d_ws, size_t ws_size,
                              hipStream_t stream)
{
    const void* h      = d_in[0];
    const void* weight = d_in[1];
    const void* norm   = d_in[2];
    const int* src = (const int*)d_in[3];
    const int* dst = (const int*)d_in[4];
    const int* rel = (const int*)d_in[5];

    char* w = (char*)d_ws;
    int* flag = (int*)w;                        w += 256;
    int* gcur = (int*)w;                        w += (NCB * 4 + 255) / 256 * 256;
    int* segBase = (int*)w;                     w += ((size_t)NSEG_AL * 4 + 255) / 256 * 256;
    int* segCnt  = (int*)w;                     w += ((size_t)NSEG_AL * 4 + 255) / 256 * 256;
    unsigned long long* R = (unsigned long long*)w;  w += (size_t)NCB * CB_R_ARENA * 8;
    unsigned* packed2 = (unsigned*)w;           w += ((size_t)EMAX * 4 + 255) / 256 * 256;
    unsigned short* normS = (unsigned short*)w; w += ((size_t)EMAX * 2 + 255) / 256 * 256;
    unsigned short* hbf = (unsigned short*)w;   w += (size_t)N_NODES * DIM * 2;
    unsigned short* Wswz = (unsigned short*)w;  w += (size_t)NREL * 5120 * 2;

    k_detect<<<1, 1024, 0, stream>>>((const float*)norm, flag, gcur);

    k_split_prep<<<P1_GRID + PREP_HBLK + NREL, 256, 0, stream>>>(
        src, dst, rel, norm, gcur, R, h, weight, hbf, Wswz, flag);

    k_fine<<<NCB, 256, 0, stream>>>(gcur, R, packed2, normS, segBase, segCnt);

    k_fused2<<<(NTILE + 1) / 2, 256, 0, stream>>>(packed2, normS, hbf, Wswz,
                                                  segBase, segCnt, d_out, flag);
}